// Round 1
// baseline (235.245 us; speedup 1.0000x reference)
//
#include <hip/hip_runtime.h>
#include <hip/hip_bf16.h>
#include <math.h>

#define D_DIM 128
#define R_DIM 64
#define T_DIM 2048
#define B_DIM 8

typedef __attribute__((ext_vector_type(8))) short bf16x8;
typedef __attribute__((ext_vector_type(4))) float f32x4;

__device__ inline unsigned short f2bf(float f) {
  union { float f; unsigned int u; } v; v.f = f;
  return (unsigned short)((v.u + 0x7FFFu + ((v.u >> 16) & 1u)) >> 16);
}
__device__ inline float bf2f(unsigned short u) {
  union { unsigned int u; float f; } v; v.u = ((unsigned int)u) << 16;
  return v.f;
}

// ---------------- Kernel A: S = W W^T / sqrt(D*R) ----------------
__global__ void k_s(const float* __restrict__ W, float* __restrict__ S) {
  int gid = blockIdx.x * 256 + threadIdx.x;   // 16384 threads, one per S element
  int i = gid >> 7, j = gid & 127;
  const float* wi = W + i * R_DIM;
  const float* wj = W + j * R_DIM;
  float acc = 0.f;
#pragma unroll 8
  for (int r = 0; r < R_DIM; ++r) acc += wi[r] * wj[r];
  S[gid] = acc * 0.011048543456039806f;  // 1/sqrt(128*64)
}

// ---------------- Kernel B: Q = X*S, bf16 copies, trace partials ----------------
__global__ void __launch_bounds__(128) k_prep(
    const float* __restrict__ X, const float* __restrict__ S,
    unsigned short* __restrict__ Qb, unsigned short* __restrict__ Xb,
    unsigned short* __restrict__ Xt, float* __restrict__ part) {
  __shared__ unsigned short sS[D_DIM * D_DIM];  // S in bf16, 32 KB
  __shared__ float sx[4][D_DIM];
  __shared__ float red[128];
  const int tid = threadIdx.x;           // 128 threads = d index
  const int b = blockIdx.y;
  const int tbase = blockIdx.x * 16;     // 16 rows per block

  for (int i = tid; i < D_DIM * D_DIM; i += 128) sS[i] = f2bf(S[i]);
  __syncthreads();

  float trp = 0.f;
  for (int r0 = 0; r0 < 16; r0 += 4) {
#pragma unroll
    for (int i = 0; i < 4; ++i) {
      int t = tbase + r0 + i;
      sx[i][tid] = X[((size_t)b * T_DIM + t) * D_DIM + tid];
    }
    __syncthreads();
    float q0 = 0.f, q1 = 0.f, q2 = 0.f, q3 = 0.f;
    for (int e = 0; e < D_DIM; ++e) {
      float s = bf2f(sS[e * D_DIM + tid]);
      q0 += sx[0][e] * s; q1 += sx[1][e] * s;
      q2 += sx[2][e] * s; q3 += sx[3][e] * s;
    }
    float qa[4] = {q0, q1, q2, q3};
#pragma unroll
    for (int i = 0; i < 4; ++i) {
      int t = tbase + r0 + i;
      float x = sx[i][tid];
      size_t idx = ((size_t)b * T_DIM + t) * D_DIM + tid;
      Qb[idx] = f2bf(qa[i]);
      Xb[idx] = f2bf(x);
      Xt[((size_t)b * D_DIM + tid) * T_DIM + t] = f2bf(x);
      trp += qa[i] * x;
    }
    __syncthreads();
  }
  red[tid] = trp;
  __syncthreads();
  for (int off = 64; off > 0; off >>= 1) {
    if (tid < off) red[tid] += red[tid + off];
    __syncthreads();
  }
  if (tid == 0) part[b * 128 + blockIdx.x] = red[0];
}

// ---------------- Kernel B2: reduce trace partials (deterministic) ----------------
__global__ void k_trace(const float* __restrict__ part, float* __restrict__ trace) {
  int b = blockIdx.x;
  int tid = threadIdx.x;  // 128
  float v = part[b * 128 + tid];
  for (int m = 1; m < 64; m <<= 1) v += __shfl_xor(v, m);
  __shared__ float s2[2];
  if ((tid & 63) == 0) s2[tid >> 6] = v;
  __syncthreads();
  if (tid == 0) trace[b] = s2[0] + s2[1];
}

// ---------------- Kernel C: flash attention ----------------
// scores[t,s] = (Q[t]·X[s] - (s==t)*tr/T) / sqrt(D);  A = softmax;  Y = A·X
__global__ void __launch_bounds__(128, 2) k_attn(
    const unsigned short* __restrict__ Qb, const unsigned short* __restrict__ Xb,
    const unsigned short* __restrict__ Xt, const float* __restrict__ trace,
    float* __restrict__ out) {
  const float scale = 0.08838834764831845f;  // 1/sqrt(128)
  const int tid = threadIdx.x;
  const int wave = tid >> 6, lane = tid & 63;
  const int g = lane >> 4, c = lane & 15;
  const int b = blockIdx.y;
  const int t0 = blockIdx.x * 32 + wave * 16;  // 16 q-rows per wave

  const unsigned short* Qbb = Qb + (size_t)b * T_DIM * D_DIM;
  const unsigned short* Xbb = Xb + (size_t)b * T_DIM * D_DIM;
  const unsigned short* Xtb = Xt + (size_t)b * D_DIM * T_DIM;
  const float ctr = trace[b] * (1.0f / T_DIM) * scale;

  __shared__ short sP[2][16][64];  // per-wave P tile (16 t-rows x 64 s), bf16

  bf16x8 qf[4];
#pragma unroll
  for (int kc = 0; kc < 4; ++kc)
    qf[kc] = *(const bf16x8*)(Qbb + (t0 + c) * D_DIM + kc * 32 + g * 8);

  f32x4 acc[8];
#pragma unroll
  for (int dt = 0; dt < 8; ++dt) acc[dt] = (f32x4){0.f, 0.f, 0.f, 0.f};
  float rs[4] = {0.f, 0.f, 0.f, 0.f};

  for (int sb = 0; sb < T_DIM; sb += 64) {
    // ---- QK^T + exp + stage P ----
#pragma unroll
    for (int st = 0; st < 4; ++st) {
      f32x4 sc = (f32x4){0.f, 0.f, 0.f, 0.f};
#pragma unroll
      for (int kc = 0; kc < 4; ++kc) {
        bf16x8 kf = *(const bf16x8*)(Xbb + (sb + st * 16 + c) * D_DIM + kc * 32 + g * 8);
        sc = __builtin_amdgcn_mfma_f32_16x16x32_bf16(qf[kc], kf, sc, 0, 0, 0);
      }
      const int s = sb + st * 16 + c;
#pragma unroll
      for (int r = 0; r < 4; ++r) {
        int t = t0 + g * 4 + r;             // C/D layout: row=(lane>>4)*4+reg, col=lane&15
        float v = sc[r] * scale;
        if (s == t) v -= ctr;               // trace-centering on the diagonal
        float p = __expf(v);                // |v| < ~0.5 -> no max-subtraction needed
        rs[r] += p;
        sP[wave][g * 4 + r][st * 16 + c] = (short)f2bf(p);
      }
    }
    // ---- P·V (same-wave LDS, DS pipe is in-order: no barrier needed) ----
    bf16x8 pf[2];
#pragma unroll
    for (int k2 = 0; k2 < 2; ++k2)
      pf[k2] = *(const bf16x8*)&sP[wave][c][k2 * 32 + g * 8];
#pragma unroll
    for (int dt = 0; dt < 8; ++dt) {
#pragma unroll
      for (int k2 = 0; k2 < 2; ++k2) {
        bf16x8 vf = *(const bf16x8*)(Xtb + (dt * 16 + c) * T_DIM + sb + k2 * 32 + g * 8);
        acc[dt] = __builtin_amdgcn_mfma_f32_16x16x32_bf16(pf[k2], vf, acc[dt], 0, 0, 0);
      }
    }
  }

  // ---- normalize + store ----
  float inv[4];
#pragma unroll
  for (int r = 0; r < 4; ++r) {
    float v = rs[r];
    v += __shfl_xor(v, 1); v += __shfl_xor(v, 2);
    v += __shfl_xor(v, 4); v += __shfl_xor(v, 8);
    inv[r] = 1.0f / v;
  }
  float* outb = out + (size_t)b * T_DIM * D_DIM;
#pragma unroll
  for (int dt = 0; dt < 8; ++dt) {
#pragma unroll
    for (int r = 0; r < 4; ++r) {
      outb[(t0 + g * 4 + r) * D_DIM + dt * 16 + c] = acc[dt][r] * inv[r];
    }
  }
}

extern "C" void kernel_launch(void* const* d_in, const int* in_sizes, int n_in,
                              void* d_out, int out_size, void* d_ws, size_t ws_size,
                              hipStream_t stream) {
  const float* X = (const float*)d_in[0];  // (8, 2048, 128) fp32
  const float* W = (const float*)d_in[1];  // (128, 64) fp32
  float* out = (float*)d_out;              // (8, 2048, 128) fp32
  char* ws = (char*)d_ws;

  float* S            = (float*)(ws);                       // 65536 B
  float* trace        = (float*)(ws + 65536);               // 32 B
  float* part         = (float*)(ws + 65792);               // 4096 B
  unsigned short* Qb  = (unsigned short*)(ws + 131072);     // 4 MB bf16 Q
  unsigned short* Xb  = (unsigned short*)(ws + 131072 + 4194304);      // 4 MB bf16 X
  unsigned short* Xt  = (unsigned short*)(ws + 131072 + 2 * 4194304);  // 4 MB bf16 X^T
  // total ws use: ~12.2 MB

  k_s<<<64, 256, 0, stream>>>(W, S);
  k_prep<<<dim3(T_DIM / 16, B_DIM), 128, 0, stream>>>(X, S, Qb, Xb, Xt, part);
  k_trace<<<B_DIM, 128, 0, stream>>>(part, trace);
  k_attn<<<dim3(T_DIM / 32, B_DIM), 128, 0, stream>>>(Qb, Xb, Xt, trace, out);
}

// Round 2
// 160.864 us; speedup vs baseline: 1.4624x; 1.4624x over previous
//
#include <hip/hip_runtime.h>
#include <hip/hip_bf16.h>
#include <math.h>

#define D_DIM 128
#define R_DIM 64
#define T_DIM 2048
#define B_DIM 8
#define NS 4                       // split-K factor over the s dimension
#define SCHUNK (T_DIM / NS)        // 512

typedef __attribute__((ext_vector_type(8))) short bf16x8;
typedef __attribute__((ext_vector_type(4))) short s16x4;
typedef __attribute__((ext_vector_type(4))) float f32x4;

__device__ inline unsigned short f2bf(float f) {
  union { float f; unsigned int u; } v; v.f = f;
  return (unsigned short)((v.u + 0x7FFFu + ((v.u >> 16) & 1u)) >> 16);
}
__device__ inline float bf2f(unsigned short u) {
  union { unsigned int u; float f; } v; v.u = ((unsigned int)u) << 16;
  return v.f;
}

// ---------------- Kernel A: S = W W^T / sqrt(D*R) ----------------
__global__ void k_s(const float* __restrict__ W, float* __restrict__ S) {
  int gid = blockIdx.x * 256 + threadIdx.x;
  int i = gid >> 7, j = gid & 127;
  const float* wi = W + i * R_DIM;
  const float* wj = W + j * R_DIM;
  float acc = 0.f;
#pragma unroll 8
  for (int r = 0; r < R_DIM; ++r) acc += wi[r] * wj[r];
  S[gid] = acc * 0.011048543456039806f;  // 1/sqrt(128*64)
}

// ---------------- Kernel B: Q = X*S, bf16 copies, trace partials ----------------
__global__ void __launch_bounds__(128) k_prep(
    const float* __restrict__ X, const float* __restrict__ S,
    unsigned short* __restrict__ Qb, unsigned short* __restrict__ Xb,
    unsigned short* __restrict__ Xt, float* __restrict__ part) {
  __shared__ unsigned short sS[D_DIM * D_DIM];
  __shared__ float sx[4][D_DIM];
  __shared__ float red[128];
  const int tid = threadIdx.x;
  const int b = blockIdx.y;
  const int tbase = blockIdx.x * 16;

  for (int i = tid; i < D_DIM * D_DIM; i += 128) sS[i] = f2bf(S[i]);
  __syncthreads();

  float trp = 0.f;
  for (int r0 = 0; r0 < 16; r0 += 4) {
#pragma unroll
    for (int i = 0; i < 4; ++i) {
      int t = tbase + r0 + i;
      sx[i][tid] = X[((size_t)b * T_DIM + t) * D_DIM + tid];
    }
    __syncthreads();
    float q0 = 0.f, q1 = 0.f, q2 = 0.f, q3 = 0.f;
    for (int e = 0; e < D_DIM; ++e) {
      float s = bf2f(sS[e * D_DIM + tid]);
      q0 += sx[0][e] * s; q1 += sx[1][e] * s;
      q2 += sx[2][e] * s; q3 += sx[3][e] * s;
    }
    float qa[4] = {q0, q1, q2, q3};
#pragma unroll
    for (int i = 0; i < 4; ++i) {
      int t = tbase + r0 + i;
      float x = sx[i][tid];
      size_t idx = ((size_t)b * T_DIM + t) * D_DIM + tid;
      Qb[idx] = f2bf(qa[i]);
      Xb[idx] = f2bf(x);
      Xt[((size_t)b * D_DIM + tid) * T_DIM + t] = f2bf(x);
      trp += qa[i] * x;
    }
    __syncthreads();
  }
  red[tid] = trp;
  __syncthreads();
  for (int off = 64; off > 0; off >>= 1) {
    if (tid < off) red[tid] += red[tid + off];
    __syncthreads();
  }
  if (tid == 0) part[b * 128 + blockIdx.x] = red[0];
}

// ---------------- Kernel B2: reduce trace partials ----------------
__global__ void k_trace(const float* __restrict__ part, float* __restrict__ trace) {
  int b = blockIdx.x;
  int tid = threadIdx.x;
  float v = part[b * 128 + tid];
  for (int m = 1; m < 64; m <<= 1) v += __shfl_xor(v, m);
  __shared__ float s2[2];
  if ((tid & 63) == 0) s2[tid >> 6] = v;
  __syncthreads();
  if (tid == 0) trace[b] = s2[0] + s2[1];
}

// ---------------- Kernel C: flash attention, split-K over s ----------------
// Each block: 4 waves x 16 q-rows = 64 q-rows, one s-chunk of 512.
// No max-subtraction needed (|scores| < ~0.5) -> partials combine by addition.
__global__ void __launch_bounds__(256, 4) k_attn(
    const unsigned short* __restrict__ Qb, const unsigned short* __restrict__ Xb,
    const unsigned short* __restrict__ Xt, const float* __restrict__ trace,
    unsigned short* __restrict__ accp, float* __restrict__ rsp) {
  const float scale = 0.08838834764831845f;  // 1/sqrt(128)
  const int tid = threadIdx.x;
  const int wave = tid >> 6, lane = tid & 63;
  const int g = lane >> 4, c = lane & 15;
  const int b = blockIdx.z;
  const int ns = blockIdx.y;
  const int t0 = blockIdx.x * 64 + wave * 16;

  const unsigned short* Qbb = Qb + (size_t)b * T_DIM * D_DIM;
  const unsigned short* Xbb = Xb + (size_t)b * T_DIM * D_DIM;
  const unsigned short* Xtb = Xt + (size_t)b * D_DIM * T_DIM;
  const float ctr = trace[b] * (1.0f / T_DIM) * scale;

  __shared__ short sP[4][16][72];  // per-wave P tile, padded (72) to break row-alias

  bf16x8 qf[4];
#pragma unroll
  for (int kc = 0; kc < 4; ++kc)
    qf[kc] = *(const bf16x8*)(Qbb + (t0 + c) * D_DIM + kc * 32 + g * 8);

  f32x4 acc[8];
#pragma unroll
  for (int dt = 0; dt < 8; ++dt) acc[dt] = (f32x4){0.f, 0.f, 0.f, 0.f};
  float rs[4] = {0.f, 0.f, 0.f, 0.f};

  const int s_beg = ns * SCHUNK;
  for (int sb = s_beg; sb < s_beg + SCHUNK; sb += 64) {
    // ---- QK^T + exp + stage P ----
#pragma unroll
    for (int st = 0; st < 4; ++st) {
      f32x4 sc = (f32x4){0.f, 0.f, 0.f, 0.f};
#pragma unroll
      for (int kc = 0; kc < 4; ++kc) {
        bf16x8 kf = *(const bf16x8*)(Xbb + (sb + st * 16 + c) * D_DIM + kc * 32 + g * 8);
        sc = __builtin_amdgcn_mfma_f32_16x16x32_bf16(qf[kc], kf, sc, 0, 0, 0);
      }
      const int s = sb + st * 16 + c;
#pragma unroll
      for (int r = 0; r < 4; ++r) {
        int t = t0 + g * 4 + r;             // C/D layout: row=(lane>>4)*4+reg, col=lane&15
        float v = sc[r] * scale;
        if (s == t) v -= ctr;               // trace-centering on the diagonal
        float p = __expf(v);
        rs[r] += p;
        sP[wave][g * 4 + r][st * 16 + c] = (short)f2bf(p);
      }
    }
    // ---- P·V (same-wave LDS, in-order DS pipe: no barrier) ----
    bf16x8 pf[2];
#pragma unroll
    for (int k2 = 0; k2 < 2; ++k2)
      pf[k2] = *(const bf16x8*)&sP[wave][c][k2 * 32 + g * 8];
#pragma unroll
    for (int dt = 0; dt < 8; ++dt) {
#pragma unroll
      for (int k2 = 0; k2 < 2; ++k2) {
        bf16x8 vf = *(const bf16x8*)(Xtb + (dt * 16 + c) * T_DIM + sb + k2 * 32 + g * 8);
        acc[dt] = __builtin_amdgcn_mfma_f32_16x16x32_bf16(pf[k2], vf, acc[dt], 0, 0, 0);
      }
    }
  }

  // ---- reduce row-sums over the 16 columns, write partials ----
#pragma unroll
  for (int r = 0; r < 4; ++r) {
    float v = rs[r];
    v += __shfl_xor(v, 1); v += __shfl_xor(v, 2);
    v += __shfl_xor(v, 4); v += __shfl_xor(v, 8);
    rs[r] = v;
  }
  const size_t pbase = ((size_t)(b * NS + ns)) * T_DIM * D_DIM;
#pragma unroll
  for (int dt = 0; dt < 8; ++dt) {
#pragma unroll
    for (int r = 0; r < 4; ++r) {
      accp[pbase + (size_t)(t0 + g * 4 + r) * D_DIM + dt * 16 + c] = f2bf(acc[dt][r]);
    }
  }
  if (c == 0) {
#pragma unroll
    for (int r = 0; r < 4; ++r)
      rsp[(b * NS + ns) * T_DIM + t0 + g * 4 + r] = rs[r];
  }
}

// ---------------- Kernel D: combine split-K partials, normalize ----------------
__global__ void __launch_bounds__(256) k_comb(
    const unsigned short* __restrict__ accp, const float* __restrict__ rsp,
    float* __restrict__ out) {
  int gid = blockIdx.x * 256 + threadIdx.x;   // 524288 threads, 4 elems each
  int base = gid * 4;
  int d = base & 127;
  int t = (base >> 7) & (T_DIM - 1);
  int b = base >> 18;
  float num0 = 0.f, num1 = 0.f, num2 = 0.f, num3 = 0.f, den = 0.f;
#pragma unroll
  for (int ns = 0; ns < NS; ++ns) {
    const unsigned short* p =
        accp + (((size_t)(b * NS + ns)) * T_DIM + t) * D_DIM + d;
    s16x4 v = *(const s16x4*)p;
    num0 += bf2f((unsigned short)v[0]);
    num1 += bf2f((unsigned short)v[1]);
    num2 += bf2f((unsigned short)v[2]);
    num3 += bf2f((unsigned short)v[3]);
    den += rsp[(b * NS + ns) * T_DIM + t];
  }
  float inv = 1.0f / den;
  f32x4 o = (f32x4){num0 * inv, num1 * inv, num2 * inv, num3 * inv};
  *(f32x4*)(out + base) = o;
}

extern "C" void kernel_launch(void* const* d_in, const int* in_sizes, int n_in,
                              void* d_out, int out_size, void* d_ws, size_t ws_size,
                              hipStream_t stream) {
  const float* X = (const float*)d_in[0];  // (8, 2048, 128) fp32
  const float* W = (const float*)d_in[1];  // (128, 64) fp32
  float* out = (float*)d_out;
  char* ws = (char*)d_ws;

  float* S           = (float*)(ws);                              // 64 KB
  float* trace       = (float*)(ws + 65536);                      // 32 B
  float* part        = (float*)(ws + 65792);                      // 4 KB
  unsigned short* Qb = (unsigned short*)(ws + 131072);            // 4 MB
  unsigned short* Xb = (unsigned short*)(ws + 131072 + 4194304);  // 4 MB
  unsigned short* Xt = (unsigned short*)(ws + 131072 + 2 * 4194304);  // 4 MB
  unsigned short* accp = (unsigned short*)(ws + 131072 + 3 * 4194304);       // 16 MB bf16
  float* rsp         = (float*)(ws + 131072 + 3 * 4194304 + 16777216);       // 256 KB
  // total ws use: ~29.8 MB

  k_s<<<64, 256, 0, stream>>>(W, S);
  k_prep<<<dim3(T_DIM / 16, B_DIM), 128, 0, stream>>>(X, S, Qb, Xb, Xt, part);
  k_trace<<<B_DIM, 128, 0, stream>>>(part, trace);
  k_attn<<<dim3(T_DIM / 64, NS, B_DIM), 256, 0, stream>>>(Qb, Xb, Xt, trace, accp, rsp);
  k_comb<<<(B_DIM * T_DIM * D_DIM / 4) / 256, 256, 0, stream>>>(accp, rsp, out);
}

// Round 3
// 80.672 us; speedup vs baseline: 2.9161x; 1.9941x over previous
//
#include <hip/hip_runtime.h>
#include <hip/hip_bf16.h>
#include <math.h>

#define D_DIM 128
#define R_DIM 64
#define T_DIM 2048
#define B_DIM 8
#define NS 4                       // split-K factor over the s dimension
#define SCHUNK (T_DIM / NS)        // 512
#define SBLK 32                    // s-tile per iteration
#define NIT (SCHUNK / SBLK)        // 16

typedef __attribute__((ext_vector_type(8))) short bf16x8;
typedef __attribute__((ext_vector_type(4))) short s16x4;
typedef __attribute__((ext_vector_type(4))) float f32x4;

__device__ inline unsigned short f2bf(float f) {
  union { float f; unsigned int u; } v; v.f = f;
  return (unsigned short)((v.u + 0x7FFFu + ((v.u >> 16) & 1u)) >> 16);
}
__device__ inline float bf2f(unsigned short u) {
  union { unsigned int u; float f; } v; v.u = ((unsigned int)u) << 16;
  return v.f;
}

// async global->LDS, 16B per lane; LDS dest = uniform base + lane*16
__device__ inline void async16(short* l, const unsigned short* g) {
  __builtin_amdgcn_global_load_lds(
      (const __attribute__((address_space(1))) unsigned int*)g,
      (__attribute__((address_space(3))) unsigned int*)l, 16, 0, 0);
}

// ---------------- Kernel A: S = W W^T / sqrt(D*R) ----------------
__global__ void k_s(const float* __restrict__ W, float* __restrict__ S) {
  int gid = blockIdx.x * 256 + threadIdx.x;
  int i = gid >> 7, j = gid & 127;
  const float* wi = W + i * R_DIM;
  const float* wj = W + j * R_DIM;
  float acc = 0.f;
#pragma unroll 8
  for (int r = 0; r < R_DIM; ++r) acc += wi[r] * wj[r];
  S[gid] = acc * 0.011048543456039806f;  // 1/sqrt(128*64)
}

// ---------------- Kernel B: Q = X*S, bf16 copies, trace partials ----------------
__global__ void __launch_bounds__(128) k_prep(
    const float* __restrict__ X, const float* __restrict__ S,
    unsigned short* __restrict__ Qb, unsigned short* __restrict__ Xb,
    unsigned short* __restrict__ Xt, float* __restrict__ part) {
  __shared__ unsigned short sS[D_DIM * D_DIM];
  __shared__ float sx[4][D_DIM];
  __shared__ float red[128];
  const int tid = threadIdx.x;
  const int b = blockIdx.y;
  const int tbase = blockIdx.x * 16;

  for (int i = tid; i < D_DIM * D_DIM; i += 128) sS[i] = f2bf(S[i]);
  __syncthreads();

  float trp = 0.f;
  for (int r0 = 0; r0 < 16; r0 += 4) {
#pragma unroll
    for (int i = 0; i < 4; ++i) {
      int t = tbase + r0 + i;
      sx[i][tid] = X[((size_t)b * T_DIM + t) * D_DIM + tid];
    }
    __syncthreads();
    float q0 = 0.f, q1 = 0.f, q2 = 0.f, q3 = 0.f;
    for (int e = 0; e < D_DIM; ++e) {
      float s = bf2f(sS[e * D_DIM + tid]);
      q0 += sx[0][e] * s; q1 += sx[1][e] * s;
      q2 += sx[2][e] * s; q3 += sx[3][e] * s;
    }
    float qa[4] = {q0, q1, q2, q3};
#pragma unroll
    for (int i = 0; i < 4; ++i) {
      int t = tbase + r0 + i;
      float x = sx[i][tid];
      size_t idx = ((size_t)b * T_DIM + t) * D_DIM + tid;
      Qb[idx] = f2bf(qa[i]);
      Xb[idx] = f2bf(x);
      Xt[((size_t)b * D_DIM + tid) * T_DIM + t] = f2bf(x);
      trp += qa[i] * x;
    }
    __syncthreads();
  }
  red[tid] = trp;
  __syncthreads();
  for (int off = 64; off > 0; off >>= 1) {
    if (tid < off) red[tid] += red[tid + off];
    __syncthreads();
  }
  if (tid == 0) part[b * 128 + blockIdx.x] = red[0];
}

// ---------------- Kernel B2: reduce trace partials ----------------
__global__ void k_trace(const float* __restrict__ part, float* __restrict__ trace) {
  int b = blockIdx.x;
  int tid = threadIdx.x;
  float v = part[b * 128 + tid];
  for (int m = 1; m < 64; m <<= 1) v += __shfl_xor(v, m);
  __shared__ float s2[2];
  if ((tid & 63) == 0) s2[tid >> 6] = v;
  __syncthreads();
  if (tid == 0) trace[b] = s2[0] + s2[1];
}

// ---------------- Kernel C: flash attention, LDS-staged, double-buffered ----------------
// Block: 2 waves x 32 q-rows = 64 q-rows; s-chunk SCHUNK (split-K over blockIdx.y).
// K tile [32][128] bf16 (256B rows), XOR-swizzled chunks: slot = lc ^ (row&7).
// Vt tile [128][32] bf16 (64B rows), XOR-swizzled: slot = lc ^ (row&3).
// Staged via global_load_lds (linear LDS dest, inverse-swizzled global src).
__global__ void __launch_bounds__(128, 3) k_attn(
    const unsigned short* __restrict__ Qb, const unsigned short* __restrict__ Xb,
    const unsigned short* __restrict__ Xt, const float* __restrict__ trace,
    unsigned short* __restrict__ accp, float* __restrict__ rsp) {
  const float KE = 0.08838834764831845f * 1.4426950408889634f;  // scale * log2e
  const int tid = threadIdx.x;
  const int wave = tid >> 6, lane = tid & 63;
  const int g = lane >> 4, c = lane & 15;
  const int b = blockIdx.z;
  const int ns = blockIdx.y;
  const int t0w = blockIdx.x * 64 + wave * 32;   // 32 q-rows per wave

  const unsigned short* Qbb = Qb + (size_t)b * T_DIM * D_DIM;
  const unsigned short* Xbb = Xb + (size_t)b * T_DIM * D_DIM;
  const unsigned short* Xtb = Xt + (size_t)b * D_DIM * T_DIM;
  const float ctrK = trace[b] * (1.0f / T_DIM) * KE;

  __shared__ short sKs[2][SBLK * D_DIM];   // 2 x 8 KB
  __shared__ short sVs[2][D_DIM * SBLK];   // 2 x 8 KB
  __shared__ short sPa[2][32][40];         // per-wave P tile, 80B rows

  // per-lane swizzled ds_read offsets (in shorts)
  int oK[4], oV;
#pragma unroll
  for (int kc = 0; kc < 4; ++kc)
    oK[kc] = c * 128 + (((kc * 4 + g) ^ (c & 7)) * 8);
  oV = c * 32 + ((g ^ (c & 3)) * 8);

  // Q fragments: 2 t-sub-tiles x 4 k-chunks
  bf16x8 qf[2][4];
#pragma unroll
  for (int tt = 0; tt < 2; ++tt)
#pragma unroll
    for (int kc = 0; kc < 4; ++kc)
      qf[tt][kc] = *(const bf16x8*)(Qbb + (size_t)(t0w + tt * 16 + c) * D_DIM + kc * 32 + g * 8);

  f32x4 acc[2][8];
#pragma unroll
  for (int tt = 0; tt < 2; ++tt)
#pragma unroll
    for (int dt = 0; dt < 8; ++dt) acc[tt][dt] = (f32x4){0.f, 0.f, 0.f, 0.f};
  float rs[2][4] = {{0.f, 0.f, 0.f, 0.f}, {0.f, 0.f, 0.f, 0.f}};

  const int s_beg = ns * SCHUNK;

  // ---- staging helper (8 global_load_lds issues per wave) ----
  auto stage = [&](int buf, int sb) {
    // K tile: 512 chunks of 16B; wave w covers chunks w*256 + q*64 + lane
#pragma unroll
    for (int q = 0; q < 4; ++q) {
      int j = wave * 256 + q * 64 + lane;
      int row = j >> 4, sc = j & 15;
      int lc = sc ^ (row & 7);
      async16(&sKs[buf][(wave * 256 + q * 64) * 8],
              Xbb + (size_t)(sb + row) * D_DIM + lc * 8);
    }
    // Vt tile: 512 chunks; rows are d (0..127), 4 chunks per row
#pragma unroll
    for (int q = 0; q < 4; ++q) {
      int j = wave * 256 + q * 64 + lane;
      int row = j >> 2, sc = j & 3;
      int lc = sc ^ (row & 3);
      async16(&sVs[buf][(wave * 256 + q * 64) * 8],
              Xtb + (size_t)row * T_DIM + sb + lc * 8);
    }
  };

  stage(0, s_beg);
  __syncthreads();

  for (int it = 0; it < NIT; ++it) {
    const int buf = it & 1;
    const int sb = s_beg + it * SBLK;
    if (it < NIT - 1) stage(buf ^ 1, sb + SBLK);

    const short* kb = &sKs[buf][0];
    const short* vb = &sVs[buf][0];

    // ---- QK^T + exp + stage P ----
#pragma unroll
    for (int st = 0; st < 2; ++st) {
      bf16x8 kf[4];
#pragma unroll
      for (int kc = 0; kc < 4; ++kc)
        kf[kc] = *(const bf16x8*)(kb + oK[kc] + st * 16 * 128);
      f32x4 sc0 = (f32x4){0.f, 0.f, 0.f, 0.f};
      f32x4 sc1 = (f32x4){0.f, 0.f, 0.f, 0.f};
#pragma unroll
      for (int kc = 0; kc < 4; ++kc) {
        sc0 = __builtin_amdgcn_mfma_f32_16x16x32_bf16(qf[0][kc], kf[kc], sc0, 0, 0, 0);
        sc1 = __builtin_amdgcn_mfma_f32_16x16x32_bf16(qf[1][kc], kf[kc], sc1, 0, 0, 0);
      }
      const int s = sb + st * 16 + c;
#pragma unroll
      for (int r = 0; r < 4; ++r) {
        // tt = 0
        {
          int t = t0w + g * 4 + r;
          float v = sc0[r] * KE;
          if (s == t) v -= ctrK;
          float p = exp2f(v);
          rs[0][r] += p;
          sPa[wave][g * 4 + r][st * 16 + c] = (short)f2bf(p);
        }
        // tt = 1
        {
          int t = t0w + 16 + g * 4 + r;
          float v = sc1[r] * KE;
          if (s == t) v -= ctrK;
          float p = exp2f(v);
          rs[1][r] += p;
          sPa[wave][16 + g * 4 + r][st * 16 + c] = (short)f2bf(p);
        }
      }
    }

    // ---- P·V (same-wave LDS write->read; compiler orders via lgkmcnt) ----
    bf16x8 pf[2];
#pragma unroll
    for (int tt = 0; tt < 2; ++tt)
      pf[tt] = *(const bf16x8*)&sPa[wave][tt * 16 + c][g * 8];
#pragma unroll
    for (int dt = 0; dt < 8; ++dt) {
      bf16x8 vf = *(const bf16x8*)(vb + oV + dt * 16 * 32);
      acc[0][dt] = __builtin_amdgcn_mfma_f32_16x16x32_bf16(pf[0], vf, acc[0][dt], 0, 0, 0);
      acc[1][dt] = __builtin_amdgcn_mfma_f32_16x16x32_bf16(pf[1], vf, acc[1][dt], 0, 0, 0);
    }

    __syncthreads();   // staged buf^1 complete (vmcnt drained) + all reads of buf done
  }

  // ---- reduce row-sums over the 16 columns, write partials ----
#pragma unroll
  for (int tt = 0; tt < 2; ++tt)
#pragma unroll
    for (int r = 0; r < 4; ++r) {
      float v = rs[tt][r];
      v += __shfl_xor(v, 1); v += __shfl_xor(v, 2);
      v += __shfl_xor(v, 4); v += __shfl_xor(v, 8);
      rs[tt][r] = v;
    }
  const size_t pbase = ((size_t)(b * NS + ns)) * T_DIM * D_DIM;
#pragma unroll
  for (int tt = 0; tt < 2; ++tt)
#pragma unroll
    for (int dt = 0; dt < 8; ++dt)
#pragma unroll
      for (int r = 0; r < 4; ++r)
        accp[pbase + (size_t)(t0w + tt * 16 + g * 4 + r) * D_DIM + dt * 16 + c] =
            f2bf(acc[tt][dt][r]);
  if (c == 0) {
#pragma unroll
    for (int tt = 0; tt < 2; ++tt)
#pragma unroll
      for (int r = 0; r < 4; ++r)
        rsp[(b * NS + ns) * T_DIM + t0w + tt * 16 + g * 4 + r] = rs[tt][r];
  }
}

// ---------------- Kernel D: combine split-K partials, normalize ----------------
__global__ void __launch_bounds__(256) k_comb(
    const unsigned short* __restrict__ accp, const float* __restrict__ rsp,
    float* __restrict__ out) {
  int gid = blockIdx.x * 256 + threadIdx.x;
  int base = gid * 4;
  int d = base & 127;
  int t = (base >> 7) & (T_DIM - 1);
  int b = base >> 18;
  float num0 = 0.f, num1 = 0.f, num2 = 0.f, num3 = 0.f, den = 0.f;
#pragma unroll
  for (int ns = 0; ns < NS; ++ns) {
    const unsigned short* p =
        accp + (((size_t)(b * NS + ns)) * T_DIM + t) * D_DIM + d;
    s16x4 v = *(const s16x4*)p;
    num0 += bf2f((unsigned short)v[0]);
    num1 += bf2f((unsigned short)v[1]);
    num2 += bf2f((unsigned short)v[2]);
    num3 += bf2f((unsigned short)v[3]);
    den += rsp[(b * NS + ns) * T_DIM + t];
  }
  float inv = 1.0f / den;
  f32x4 o = (f32x4){num0 * inv, num1 * inv, num2 * inv, num3 * inv};
  *(f32x4*)(out + base) = o;
}

extern "C" void kernel_launch(void* const* d_in, const int* in_sizes, int n_in,
                              void* d_out, int out_size, void* d_ws, size_t ws_size,
                              hipStream_t stream) {
  const float* X = (const float*)d_in[0];  // (8, 2048, 128) fp32
  const float* W = (const float*)d_in[1];  // (128, 64) fp32
  float* out = (float*)d_out;
  char* ws = (char*)d_ws;

  float* S           = (float*)(ws);                              // 64 KB
  float* trace       = (float*)(ws + 65536);                      // 32 B
  float* part        = (float*)(ws + 65792);                      // 4 KB
  unsigned short* Qb = (unsigned short*)(ws + 131072);            // 4 MB
  unsigned short* Xb = (unsigned short*)(ws + 131072 + 4194304);  // 4 MB
  unsigned short* Xt = (unsigned short*)(ws + 131072 + 2 * 4194304);  // 4 MB
  unsigned short* accp = (unsigned short*)(ws + 131072 + 3 * 4194304);       // 16 MB bf16
  float* rsp         = (float*)(ws + 131072 + 3 * 4194304 + 16777216);       // 256 KB

  k_s<<<64, 256, 0, stream>>>(W, S);
  k_prep<<<dim3(T_DIM / 16, B_DIM), 128, 0, stream>>>(X, S, Qb, Xb, Xt, part);
  k_trace<<<B_DIM, 128, 0, stream>>>(part, trace);
  k_attn<<<dim3(T_DIM / 64, NS, B_DIM), 128, 0, stream>>>(Qb, Xb, Xt, trace, accp, rsp);
  k_comb<<<(B_DIM * T_DIM * D_DIM / 4) / 256, 256, 0, stream>>>(accp, rsp, out);
}

// Round 5
// 60.050 us; speedup vs baseline: 3.9175x; 1.3434x over previous
//
#include <hip/hip_runtime.h>
#include <hip/hip_bf16.h>
#include <math.h>

#define D_DIM 128
#define R_DIM 64
#define T_DIM 2048
#define B_DIM 8
#define NS 4                       // split-K factor over the s dimension
#define SCHUNK (T_DIM / NS)        // 512
#define SBLK 32                    // s-tile per iteration
#define NIT (SCHUNK / SBLK)        // 16
#define KE_CONST (0.08838834764831845f * 1.4426950408889634f)  // 1/sqrt(128) * log2(e)

typedef __attribute__((ext_vector_type(8))) short bf16x8;
typedef __attribute__((ext_vector_type(4))) short s16x4;
typedef __attribute__((ext_vector_type(4))) float f32x4;

__device__ inline unsigned short f2bf(float f) {
  union { float f; unsigned int u; } v; v.f = f;
  return (unsigned short)((v.u + 0x7FFFu + ((v.u >> 16) & 1u)) >> 16);
}
__device__ inline float bf2f(unsigned short u) {
  union { unsigned int u; float f; } v; v.u = ((unsigned int)u) << 16;
  return v.f;
}
// packed RNE f32->bf16 pair: low half = lo, high half = hi (T12 recipe)
__device__ inline unsigned int cvt_pk_bf16(float lo, float hi) {
  unsigned int r;
  asm("v_cvt_pk_bf16_f32 %0, %1, %2" : "=v"(r) : "v"(lo), "v"(hi));
  return r;
}

// async global->LDS, 16B per lane; LDS dest = wave-uniform base + lane*16
__device__ inline void async16(const short* l, const unsigned short* g) {
  __builtin_amdgcn_global_load_lds(
      (const __attribute__((address_space(1))) unsigned int*)g,
      (__attribute__((address_space(3))) unsigned int*)l, 16, 0, 0);
}

// ---------------- Kernel A: S = W W^T / sqrt(D*R), bf16 out ----------------
__global__ void k_s(const float* __restrict__ W, unsigned short* __restrict__ Sb) {
  int gid = blockIdx.x * 256 + threadIdx.x;
  int i = gid >> 7, j = gid & 127;
  const float* wi = W + i * R_DIM;
  const float* wj = W + j * R_DIM;
  float acc = 0.f;
#pragma unroll 8
  for (int r = 0; r < R_DIM; ++r) acc += wi[r] * wj[r];
  Sb[gid] = f2bf(acc * 0.011048543456039806f);  // 1/sqrt(128*64)
}

// ---------------- Kernel B: MFMA Q = X*S (pre-scaled), Xb, Xt, trace ----------------
// 2 waves/block, 16 t-rows/wave. S symmetric: B-frags read S row-major DIRECT from
// global (L2-hot, no LDS staging -> no async/barrier hazard).
__global__ void __launch_bounds__(128) k_prep(
    const float* __restrict__ X, const unsigned short* __restrict__ Sb,
    float* __restrict__ Qf, unsigned short* __restrict__ Xb,
    unsigned short* __restrict__ Xt, float* __restrict__ part) {
  const int tid = threadIdx.x;
  const int w = tid >> 6, lane = tid & 63;
  const int g = lane >> 4, c = lane & 15;
  const int b = blockIdx.y;
  const int t0 = blockIdx.x * 32;
  const int tw = t0 + w * 16;           // this wave's 16 rows

  __shared__ __align__(16) short xbT[D_DIM * 32];   // [e][t-local], 8 KB
  __shared__ float red[2];

  // load X rows, cvt to bf16 frags, write Xb, fill xbT transpose
  union FU { unsigned int wd[4]; bf16x8 v; };
  bf16x8 xf[4];
#pragma unroll
  for (int kc = 0; kc < 4; ++kc) {
    const float* xp = X + ((size_t)(b * T_DIM + tw + c)) * D_DIM + kc * 32 + g * 8;
    f32x4 a = *(const f32x4*)xp;
    f32x4 bb = *(const f32x4*)(xp + 4);
    FU f;
    f.wd[0] = cvt_pk_bf16(a[0], a[1]);
    f.wd[1] = cvt_pk_bf16(a[2], a[3]);
    f.wd[2] = cvt_pk_bf16(bb[0], bb[1]);
    f.wd[3] = cvt_pk_bf16(bb[2], bb[3]);
    xf[kc] = f.v;
    *(bf16x8*)(Xb + ((size_t)(b * T_DIM + tw + c)) * D_DIM + kc * 32 + g * 8) = f.v;
#pragma unroll
    for (int jw = 0; jw < 4; ++jw) {
      unsigned int wv = f.wd[jw];
      int e = kc * 32 + g * 8 + jw * 2;
      xbT[(e + 0) * 32 + w * 16 + c] = (short)wv;
      xbT[(e + 1) * 32 + w * 16 + c] = (short)(wv >> 16);
    }
  }

  // MFMA: acc[dc] = X(16 rows) * S, B-frags direct from global (symmetric S)
  f32x4 acc[8];
#pragma unroll
  for (int dc = 0; dc < 8; ++dc) acc[dc] = (f32x4){0.f, 0.f, 0.f, 0.f};
#pragma unroll
  for (int dc = 0; dc < 8; ++dc) {
    bf16x8 sf[4];
#pragma unroll
    for (int kc = 0; kc < 4; ++kc)
      sf[kc] = *(const bf16x8*)(Sb + (size_t)(dc * 16 + c) * D_DIM + kc * 32 + g * 8);
#pragma unroll
    for (int kc = 0; kc < 4; ++kc)
      acc[dc] = __builtin_amdgcn_mfma_f32_16x16x32_bf16(xf[kc], sf[kc], acc[dc], 0, 0, 0);
  }

  __syncthreads();   // xbT complete (both waves; real 2-wave barrier)

  // trace partial (unscaled) + store Q pre-scaled by KE as fp32
  float trp = 0.f;
#pragma unroll
  for (int dc = 0; dc < 8; ++dc)
#pragma unroll
    for (int r = 0; r < 4; ++r) {
      float q = acc[dc][r];
      float x = bf2f((unsigned short)xbT[(dc * 16 + c) * 32 + w * 16 + g * 4 + r]);
      trp += q * x;
      Qf[((size_t)(b * T_DIM + tw + g * 4 + r)) * D_DIM + dc * 16 + c] = q * KE_CONST;
    }

  // write Xt from xbT: 4 passes x 32 rows, b128 in / b128 out
#pragma unroll
  for (int p = 0; p < 4; ++p) {
    int row = p * 32 + (tid >> 2);
    bf16x8 v = *(const bf16x8*)&xbT[row * 32 + (tid & 3) * 8];
    *(bf16x8*)(Xt + ((size_t)(b * D_DIM + row)) * T_DIM + t0 + (tid & 3) * 8) = v;
  }

  // reduce trace partial: wave shuffle -> cross-wave via LDS
  trp += __shfl_xor(trp, 1); trp += __shfl_xor(trp, 2);
  trp += __shfl_xor(trp, 4); trp += __shfl_xor(trp, 8);
  trp += __shfl_xor(trp, 16); trp += __shfl_xor(trp, 32);
  if (lane == 0) red[w] = trp;
  __syncthreads();
  if (tid == 0) part[b * 64 + blockIdx.x] = red[0] + red[1];
}

// ---------------- Kernel B2: reduce trace partials ----------------
__global__ void k_trace(const float* __restrict__ part, float* __restrict__ trace) {
  int b = blockIdx.x;
  int lane = threadIdx.x;  // 64
  float v = part[b * 64 + lane];
  v += __shfl_xor(v, 1); v += __shfl_xor(v, 2);
  v += __shfl_xor(v, 4); v += __shfl_xor(v, 8);
  v += __shfl_xor(v, 16); v += __shfl_xor(v, 32);
  if (lane == 0) trace[b] = v;
}

// ---------------- Kernel C: flash attention, LDS-staged, double-buffered ----------------
__global__ void __launch_bounds__(128, 2) k_attn(
    const float* __restrict__ Qf, const unsigned short* __restrict__ Xb,
    const unsigned short* __restrict__ Xt, const float* __restrict__ trace,
    unsigned short* __restrict__ accp, float* __restrict__ rsp) {
  const int tid = threadIdx.x;
  const int wave = tid >> 6, lane = tid & 63;
  const int g = lane >> 4, c = lane & 15;
  const int b = blockIdx.z;
  const int ns = blockIdx.y;
  const int t0w = blockIdx.x * 64 + wave * 32;   // 32 q-rows per wave

  const unsigned short* Xbb = Xb + (size_t)b * T_DIM * D_DIM;
  const unsigned short* Xtb = Xt + (size_t)b * D_DIM * T_DIM;
  const float ctrK = trace[b] * (1.0f / T_DIM) * KE_CONST;

  __shared__ __align__(16) short sKs[2][SBLK * D_DIM];   // 2 x 8 KB
  __shared__ __align__(16) short sVs[2][D_DIM * SBLK];   // 2 x 8 KB
  __shared__ __align__(16) short sPa[2][32 * 40];        // per-wave P, 80B rows, grp-XOR swz

  // swizzled ds_read offsets (shorts)
  int oK[4], oV;
#pragma unroll
  for (int kc = 0; kc < 4; ++kc)
    oK[kc] = c * 128 + (((kc * 4 + g) ^ (c & 7)) * 8);
  oV = c * 32 + ((g ^ (c & 3)) * 8);
  const int oPr = (g ^ ((c >> 2) & 3)) * 8;  // P-read grp slot

  // Q fragments from fp32 pre-scaled Q
  union FU { unsigned int wd[4]; bf16x8 v; };
  bf16x8 qf[2][4];
#pragma unroll
  for (int tt = 0; tt < 2; ++tt)
#pragma unroll
    for (int kc = 0; kc < 4; ++kc) {
      const float* qp = Qf + ((size_t)(b * T_DIM + t0w + tt * 16 + c)) * D_DIM + kc * 32 + g * 8;
      f32x4 a = *(const f32x4*)qp;
      f32x4 bb = *(const f32x4*)(qp + 4);
      FU f;
      f.wd[0] = cvt_pk_bf16(a[0], a[1]);
      f.wd[1] = cvt_pk_bf16(a[2], a[3]);
      f.wd[2] = cvt_pk_bf16(bb[0], bb[1]);
      f.wd[3] = cvt_pk_bf16(bb[2], bb[3]);
      qf[tt][kc] = f.v;
    }

  bf16x8 ones;
#pragma unroll
  for (int j = 0; j < 8; ++j) ones[j] = (short)0x3F80;  // bf16 1.0

  f32x4 acc[2][8];
#pragma unroll
  for (int tt = 0; tt < 2; ++tt)
#pragma unroll
    for (int dt = 0; dt < 8; ++dt) acc[tt][dt] = (f32x4){0.f, 0.f, 0.f, 0.f};
  f32x4 accD[2] = {(f32x4){0.f, 0.f, 0.f, 0.f}, (f32x4){0.f, 0.f, 0.f, 0.f}};

  const int s_beg = ns * SCHUNK;

  auto stage = [&](int buf, int sb) {
#pragma unroll
    for (int q = 0; q < 4; ++q) {
      int j = wave * 256 + q * 64 + lane;
      int row = j >> 4, sc = j & 15;
      int lc = sc ^ (row & 7);
      async16(&sKs[buf][(wave * 256 + q * 64) * 8],
              Xbb + (size_t)(sb + row) * D_DIM + lc * 8);
    }
#pragma unroll
    for (int q = 0; q < 4; ++q) {
      int j = wave * 256 + q * 64 + lane;
      int row = j >> 2, sc = j & 3;
      int lc = sc ^ (row & 3);
      async16(&sVs[buf][(wave * 256 + q * 64) * 8],
              Xtb + (size_t)row * T_DIM + sb + lc * 8);
    }
  };

  stage(0, s_beg);
  __syncthreads();

  for (int it = 0; it < NIT; ++it) {
    const int buf = it & 1;
    const int sb = s_beg + it * SBLK;
    if (it < NIT - 1) stage(buf ^ 1, sb + SBLK);

    const short* kb = &sKs[buf][0];
    const short* vb = &sVs[buf][0];
    const bool isdiag = (sb == t0w);   // wave-uniform: only iter containing s==t

    // ---- QK^T + exp2 + stage P (conflict-free grp-XOR layout) ----
#pragma unroll
    for (int st = 0; st < 2; ++st) {
      bf16x8 kf[4];
#pragma unroll
      for (int kc = 0; kc < 4; ++kc)
        kf[kc] = *(const bf16x8*)(kb + oK[kc] + st * 16 * 128);
      f32x4 sc0 = (f32x4){0.f, 0.f, 0.f, 0.f};
      f32x4 sc1 = (f32x4){0.f, 0.f, 0.f, 0.f};
#pragma unroll
      for (int kc = 0; kc < 4; ++kc) {
        sc0 = __builtin_amdgcn_mfma_f32_16x16x32_bf16(qf[0][kc], kf[kc], sc0, 0, 0, 0);
        sc1 = __builtin_amdgcn_mfma_f32_16x16x32_bf16(qf[1][kc], kf[kc], sc1, 0, 0, 0);
      }
      const int gp = ((st * 2 + (c >> 3)) ^ g) * 8 + (c & 7);  // swizzled col slot
#pragma unroll
      for (int tt = 0; tt < 2; ++tt) {
        f32x4 sc = tt ? sc1 : sc0;
        float p[4];
#pragma unroll
        for (int r = 0; r < 4; ++r) {
          float v = sc[r];
          if (isdiag && (st * 16 + c) == (tt * 16 + g * 4 + r)) v -= ctrK;
          p[r] = exp2f(v);
        }
        unsigned int w01 = cvt_pk_bf16(p[0], p[1]);
        unsigned int w23 = cvt_pk_bf16(p[2], p[3]);
        short* pw = &sPa[wave][(tt * 16 + g * 4) * 40 + gp];
        pw[0 * 40] = (short)w01;
        pw[1 * 40] = (short)(w01 >> 16);
        pw[2 * 40] = (short)w23;
        pw[3 * 40] = (short)(w23 >> 16);
      }
    }

    // ---- P·V + den via ones-MFMA (same-wave LDS, in-order DS pipe) ----
    bf16x8 pf[2];
#pragma unroll
    for (int tt = 0; tt < 2; ++tt)
      pf[tt] = *(const bf16x8*)&sPa[wave][(tt * 16 + c) * 40 + oPr];
    accD[0] = __builtin_amdgcn_mfma_f32_16x16x32_bf16(pf[0], ones, accD[0], 0, 0, 0);
    accD[1] = __builtin_amdgcn_mfma_f32_16x16x32_bf16(pf[1], ones, accD[1], 0, 0, 0);
#pragma unroll
    for (int dt = 0; dt < 8; ++dt) {
      bf16x8 vf = *(const bf16x8*)(vb + oV + dt * 16 * 32);
      acc[0][dt] = __builtin_amdgcn_mfma_f32_16x16x32_bf16(pf[0], vf, acc[0][dt], 0, 0, 0);
      acc[1][dt] = __builtin_amdgcn_mfma_f32_16x16x32_bf16(pf[1], vf, acc[1][dt], 0, 0, 0);
    }

    __syncthreads();   // staged buf^1 complete + all reads of buf done
  }

  // ---- write partials: num (bf16) + den (fp32, col-replicated in accD) ----
  const size_t pbase = ((size_t)(b * NS + ns)) * T_DIM * D_DIM;
#pragma unroll
  for (int tt = 0; tt < 2; ++tt)
#pragma unroll
    for (int dt = 0; dt < 8; ++dt) {
      unsigned int w01 = cvt_pk_bf16(acc[tt][dt][0], acc[tt][dt][1]);
      unsigned int w23 = cvt_pk_bf16(acc[tt][dt][2], acc[tt][dt][3]);
      size_t a0 = pbase + (size_t)(t0w + tt * 16 + g * 4) * D_DIM + dt * 16 + c;
      accp[a0 + 0 * D_DIM] = (unsigned short)w01;
      accp[a0 + 1 * D_DIM] = (unsigned short)(w01 >> 16);
      accp[a0 + 2 * D_DIM] = (unsigned short)w23;
      accp[a0 + 3 * D_DIM] = (unsigned short)(w23 >> 16);
    }
  if (c == 0) {
#pragma unroll
    for (int tt = 0; tt < 2; ++tt)
#pragma unroll
      for (int r = 0; r < 4; ++r)
        rsp[(b * NS + ns) * T_DIM + t0w + tt * 16 + g * 4 + r] = accD[tt][r];
  }
}

// ---------------- Kernel D: combine split-K partials, normalize ----------------
__global__ void __launch_bounds__(256) k_comb(
    const unsigned short* __restrict__ accp, const float* __restrict__ rsp,
    float* __restrict__ out) {
  int gid = blockIdx.x * 256 + threadIdx.x;
  int base = gid * 4;
  int d = base & 127;
  int t = (base >> 7) & (T_DIM - 1);
  int b = base >> 18;
  float num0 = 0.f, num1 = 0.f, num2 = 0.f, num3 = 0.f, den = 0.f;
#pragma unroll
  for (int ns = 0; ns < NS; ++ns) {
    const unsigned short* p =
        accp + (((size_t)(b * NS + ns)) * T_DIM + t) * D_DIM + d;
    s16x4 v = *(const s16x4*)p;
    num0 += bf2f((unsigned short)v[0]);
    num1 += bf2f((unsigned short)v[1]);
    num2 += bf2f((unsigned short)v[2]);
    num3 += bf2f((unsigned short)v[3]);
    den += rsp[(b * NS + ns) * T_DIM + t];
  }
  float inv = 1.0f / den;
  f32x4 o = (f32x4){num0 * inv, num1 * inv, num2 * inv, num3 * inv};
  *(f32x4*)(out + base) = o;
}

extern "C" void kernel_launch(void* const* d_in, const int* in_sizes, int n_in,
                              void* d_out, int out_size, void* d_ws, size_t ws_size,
                              hipStream_t stream) {
  const float* X = (const float*)d_in[0];  // (8, 2048, 128) fp32
  const float* W = (const float*)d_in[1];  // (128, 64) fp32
  float* out = (float*)d_out;
  char* ws = (char*)d_ws;

  unsigned short* Sb = (unsigned short*)(ws);                 // 32 KB bf16
  float* trace       = (float*)(ws + 32768);                  // 32 B
  float* part        = (float*)(ws + 33024);                  // 2 KB
  float* Qf          = (float*)(ws + 65536);                  // 8 MB fp32 (pre-scaled)
  unsigned short* Xb = (unsigned short*)(ws + 65536 + 8388608);              // 4 MB
  unsigned short* Xt = (unsigned short*)(ws + 65536 + 8388608 + 4194304);    // 4 MB
  unsigned short* accp = (unsigned short*)(ws + 65536 + 8388608 + 2 * 4194304);  // 16 MB
  float* rsp         = (float*)(ws + 65536 + 8388608 + 2 * 4194304 + 16777216);  // 256 KB
  // total ws use: ~28.7 MB

  k_s<<<64, 256, 0, stream>>>(W, Sb);
  k_prep<<<dim3(T_DIM / 32, B_DIM), 128, 0, stream>>>(X, Sb, Qf, Xb, Xt, part);
  k_trace<<<B_DIM, 64, 0, stream>>>(part, trace);
  k_attn<<<dim3(T_DIM / 64, NS, B_DIM), 128, 0, stream>>>(Qf, Xb, Xt, trace, accp, rsp);
  k_comb<<<(B_DIM * T_DIM * D_DIM / 4) / 256, 256, 0, stream>>>(accp, rsp, out);
}

// Round 6
// 55.426 us; speedup vs baseline: 4.2443x; 1.0834x over previous
//
#include <hip/hip_runtime.h>
#include <hip/hip_bf16.h>
#include <math.h>

#define D_DIM 128
#define R_DIM 64
#define T_DIM 2048
#define B_DIM 8
#define NS 4                       // split-K factor over the s dimension
#define SCHUNK (T_DIM / NS)        // 512
#define SBLK 32                    // s-tile per iteration
#define NIT (SCHUNK / SBLK)        // 16
#define KE_CONST (0.08838834764831845f * 1.4426950408889634f)  // 1/sqrt(128) * log2(e)

typedef __attribute__((ext_vector_type(8))) short bf16x8;
typedef __attribute__((ext_vector_type(4))) short s16x4;
typedef __attribute__((ext_vector_type(4))) float f32x4;

__device__ inline unsigned short f2bf(float f) {
  union { float f; unsigned int u; } v; v.f = f;
  return (unsigned short)((v.u + 0x7FFFu + ((v.u >> 16) & 1u)) >> 16);
}
__device__ inline float bf2f(unsigned short u) {
  union { unsigned int u; float f; } v; v.u = ((unsigned int)u) << 16;
  return v.f;
}
// packed RNE f32->bf16 pair: low half = lo, high half = hi (T12 recipe)
__device__ inline unsigned int cvt_pk_bf16(float lo, float hi) {
  unsigned int r;
  asm("v_cvt_pk_bf16_f32 %0, %1, %2" : "=v"(r) : "v"(lo), "v"(hi));
  return r;
}

// async global->LDS, 16B per lane; LDS dest = wave-uniform base + lane*16
__device__ inline void async16(const short* l, const unsigned short* g) {
  __builtin_amdgcn_global_load_lds(
      (const __attribute__((address_space(1))) unsigned int*)g,
      (__attribute__((address_space(3))) unsigned int*)l, 16, 0, 0);
}

// ---------------- Kernel A: S = W W^T / sqrt(D*R), bf16 out ----------------
__global__ void k_s(const float* __restrict__ W, unsigned short* __restrict__ Sb) {
  int gid = blockIdx.x * 256 + threadIdx.x;
  int i = gid >> 7, j = gid & 127;
  const float* wi = W + i * R_DIM;
  const float* wj = W + j * R_DIM;
  float acc = 0.f;
#pragma unroll 8
  for (int r = 0; r < R_DIM; ++r) acc += wi[r] * wj[r];
  Sb[gid] = f2bf(acc * 0.011048543456039806f);  // 1/sqrt(128*64)
}

// ---------------- Kernel B: MFMA Q = X*S (bf16, pre-scaled), Xb, Xt, trace ----------------
// 2 waves/block, 16 t-rows/wave. S symmetric: B-frags read S row-major DIRECT from
// global (L2-hot, no LDS staging).
__global__ void __launch_bounds__(128) k_prep(
    const float* __restrict__ X, const unsigned short* __restrict__ Sb,
    unsigned short* __restrict__ Qb, unsigned short* __restrict__ Xb,
    unsigned short* __restrict__ Xt, float* __restrict__ part) {
  const int tid = threadIdx.x;
  const int w = tid >> 6, lane = tid & 63;
  const int g = lane >> 4, c = lane & 15;
  const int b = blockIdx.y;
  const int t0 = blockIdx.x * 32;
  const int tw = t0 + w * 16;           // this wave's 16 rows

  __shared__ __align__(16) short xbT[D_DIM * 32];   // [e][t-local], 8 KB
  __shared__ float red[2];

  // load X rows, cvt to bf16 frags, write Xb, fill xbT transpose
  union FU { unsigned int wd[4]; bf16x8 v; };
  bf16x8 xf[4];
#pragma unroll
  for (int kc = 0; kc < 4; ++kc) {
    const float* xp = X + ((size_t)(b * T_DIM + tw + c)) * D_DIM + kc * 32 + g * 8;
    f32x4 a = *(const f32x4*)xp;
    f32x4 bb = *(const f32x4*)(xp + 4);
    FU f;
    f.wd[0] = cvt_pk_bf16(a[0], a[1]);
    f.wd[1] = cvt_pk_bf16(a[2], a[3]);
    f.wd[2] = cvt_pk_bf16(bb[0], bb[1]);
    f.wd[3] = cvt_pk_bf16(bb[2], bb[3]);
    xf[kc] = f.v;
    *(bf16x8*)(Xb + ((size_t)(b * T_DIM + tw + c)) * D_DIM + kc * 32 + g * 8) = f.v;
#pragma unroll
    for (int jw = 0; jw < 4; ++jw) {
      unsigned int wv = f.wd[jw];
      int e = kc * 32 + g * 8 + jw * 2;
      xbT[(e + 0) * 32 + w * 16 + c] = (short)wv;
      xbT[(e + 1) * 32 + w * 16 + c] = (short)(wv >> 16);
    }
  }

  // MFMA: acc[dc] = X(16 rows) * S, B-frags direct from global (symmetric S)
  f32x4 acc[8];
#pragma unroll
  for (int dc = 0; dc < 8; ++dc) acc[dc] = (f32x4){0.f, 0.f, 0.f, 0.f};
#pragma unroll
  for (int dc = 0; dc < 8; ++dc) {
    bf16x8 sf[4];
#pragma unroll
    for (int kc = 0; kc < 4; ++kc)
      sf[kc] = *(const bf16x8*)(Sb + (size_t)(dc * 16 + c) * D_DIM + kc * 32 + g * 8);
#pragma unroll
    for (int kc = 0; kc < 4; ++kc)
      acc[dc] = __builtin_amdgcn_mfma_f32_16x16x32_bf16(xf[kc], sf[kc], acc[dc], 0, 0, 0);
  }

  __syncthreads();   // xbT complete (both waves)

  // trace partial (unscaled) + store Q pre-scaled by KE as bf16
  float trp = 0.f;
#pragma unroll
  for (int dc = 0; dc < 8; ++dc)
#pragma unroll
    for (int r = 0; r < 4; ++r) {
      float q = acc[dc][r];
      float x = bf2f((unsigned short)xbT[(dc * 16 + c) * 32 + w * 16 + g * 4 + r]);
      trp += q * x;
      unsigned int pk = cvt_pk_bf16(q * KE_CONST, 0.f);
      Qb[((size_t)(b * T_DIM + tw + g * 4 + r)) * D_DIM + dc * 16 + c] = (unsigned short)pk;
    }

  // write Xt from xbT: 4 passes x 32 rows, b128 in / b128 out
#pragma unroll
  for (int p = 0; p < 4; ++p) {
    int row = p * 32 + (tid >> 2);
    bf16x8 v = *(const bf16x8*)&xbT[row * 32 + (tid & 3) * 8];
    *(bf16x8*)(Xt + ((size_t)(b * D_DIM + row)) * T_DIM + t0 + (tid & 3) * 8) = v;
  }

  // reduce trace partial: wave shuffle -> cross-wave via LDS
  trp += __shfl_xor(trp, 1); trp += __shfl_xor(trp, 2);
  trp += __shfl_xor(trp, 4); trp += __shfl_xor(trp, 8);
  trp += __shfl_xor(trp, 16); trp += __shfl_xor(trp, 32);
  if (lane == 0) red[w] = trp;
  __syncthreads();
  if (tid == 0) part[b * 64 + blockIdx.x] = red[0] + red[1];
}

// ---------------- Kernel C: flash attention, 4 waves/block, LDS-staged ----------------
__global__ void __launch_bounds__(256, 2) k_attn(
    const unsigned short* __restrict__ Qb, const unsigned short* __restrict__ Xb,
    const unsigned short* __restrict__ Xt, const float* __restrict__ part,
    unsigned short* __restrict__ accp, float* __restrict__ rsp) {
  const int tid = threadIdx.x;
  const int wave = tid >> 6, lane = tid & 63;
  const int g = lane >> 4, c = lane & 15;
  const int b = blockIdx.z;
  const int ns = blockIdx.y;
  const int t0w = blockIdx.x * 128 + wave * 32;   // 32 q-rows per wave

  const unsigned short* Qbb = Qb + (size_t)b * T_DIM * D_DIM;
  const unsigned short* Xbb = Xb + (size_t)b * T_DIM * D_DIM;
  const unsigned short* Xtb = Xt + (size_t)b * D_DIM * T_DIM;

  // inline trace reduction (per-wave redundant, L2-hot)
  float tv = part[b * 64 + lane];
  tv += __shfl_xor(tv, 1); tv += __shfl_xor(tv, 2);
  tv += __shfl_xor(tv, 4); tv += __shfl_xor(tv, 8);
  tv += __shfl_xor(tv, 16); tv += __shfl_xor(tv, 32);
  const float ctrK = tv * (1.0f / T_DIM) * KE_CONST;

  __shared__ __align__(16) short sKs[2][SBLK * D_DIM];   // 2 x 8 KB
  __shared__ __align__(16) short sVs[2][D_DIM * SBLK];   // 2 x 8 KB
  __shared__ __align__(16) short sPa[4][32 * 40];        // per-wave P, 80B rows, grp-XOR swz

  // swizzled ds_read offsets (shorts)
  int oK[4], oV;
#pragma unroll
  for (int kc = 0; kc < 4; ++kc)
    oK[kc] = c * 128 + (((kc * 4 + g) ^ (c & 7)) * 8);
  oV = c * 32 + ((g ^ (c & 3)) * 8);
  const int oPr = (g ^ ((c >> 2) & 3)) * 8;  // P-read grp slot

  // Q fragments (bf16, pre-scaled by KE)
  bf16x8 qf[2][4];
#pragma unroll
  for (int tt = 0; tt < 2; ++tt)
#pragma unroll
    for (int kc = 0; kc < 4; ++kc)
      qf[tt][kc] = *(const bf16x8*)(Qbb + (size_t)(t0w + tt * 16 + c) * D_DIM + kc * 32 + g * 8);

  bf16x8 ones;
#pragma unroll
  for (int j = 0; j < 8; ++j) ones[j] = (short)0x3F80;  // bf16 1.0

  f32x4 acc[2][8];
#pragma unroll
  for (int tt = 0; tt < 2; ++tt)
#pragma unroll
    for (int dt = 0; dt < 8; ++dt) acc[tt][dt] = (f32x4){0.f, 0.f, 0.f, 0.f};
  f32x4 accD[2] = {(f32x4){0.f, 0.f, 0.f, 0.f}, (f32x4){0.f, 0.f, 0.f, 0.f}};

  const int s_beg = ns * SCHUNK;

  // staging: 1024 16B chunks split over 4 waves (2 K-issues + 2 V-issues per lane)
  auto stage = [&](int buf, int sb) {
#pragma unroll
    for (int q = 0; q < 2; ++q) {
      int j = wave * 128 + q * 64 + lane;
      int row = j >> 4, sc = j & 15;
      int lc = sc ^ (row & 7);
      async16(&sKs[buf][(wave * 128 + q * 64) * 8],
              Xbb + (size_t)(sb + row) * D_DIM + lc * 8);
    }
#pragma unroll
    for (int q = 0; q < 2; ++q) {
      int j = wave * 128 + q * 64 + lane;
      int row = j >> 2, sc = j & 3;
      int lc = sc ^ (row & 3);
      async16(&sVs[buf][(wave * 128 + q * 64) * 8],
              Xtb + (size_t)row * T_DIM + sb + lc * 8);
    }
  };

  stage(0, s_beg);
  __syncthreads();

  for (int it = 0; it < NIT; ++it) {
    const int buf = it & 1;
    const int sb = s_beg + it * SBLK;
    if (it < NIT - 1) stage(buf ^ 1, sb + SBLK);

    const short* kb = &sKs[buf][0];
    const short* vb = &sVs[buf][0];
    const bool isdiag = (sb == t0w);   // wave-uniform: only iter containing s==t

    // ---- QK^T + exp2 + stage P (conflict-free grp-XOR layout) ----
#pragma unroll
    for (int st = 0; st < 2; ++st) {
      bf16x8 kf[4];
#pragma unroll
      for (int kc = 0; kc < 4; ++kc)
        kf[kc] = *(const bf16x8*)(kb + oK[kc] + st * 16 * 128);
      f32x4 sc0 = (f32x4){0.f, 0.f, 0.f, 0.f};
      f32x4 sc1 = (f32x4){0.f, 0.f, 0.f, 0.f};
#pragma unroll
      for (int kc = 0; kc < 4; ++kc) {
        sc0 = __builtin_amdgcn_mfma_f32_16x16x32_bf16(qf[0][kc], kf[kc], sc0, 0, 0, 0);
        sc1 = __builtin_amdgcn_mfma_f32_16x16x32_bf16(qf[1][kc], kf[kc], sc1, 0, 0, 0);
      }
      const int gp = ((st * 2 + (c >> 3)) ^ g) * 8 + (c & 7);  // swizzled col slot
#pragma unroll
      for (int tt = 0; tt < 2; ++tt) {
        f32x4 sc = tt ? sc1 : sc0;
        float p[4];
#pragma unroll
        for (int r = 0; r < 4; ++r) {
          float v = sc[r];
          if (isdiag && (st * 16 + c) == (tt * 16 + g * 4 + r)) v -= ctrK;
          p[r] = exp2f(v);
        }
        unsigned int w01 = cvt_pk_bf16(p[0], p[1]);
        unsigned int w23 = cvt_pk_bf16(p[2], p[3]);
        short* pw = &sPa[wave][(tt * 16 + g * 4) * 40 + gp];
        pw[0 * 40] = (short)w01;
        pw[1 * 40] = (short)(w01 >> 16);
        pw[2 * 40] = (short)w23;
        pw[3 * 40] = (short)(w23 >> 16);
      }
    }

    // ---- P·V + den via ones-MFMA (same-wave LDS, in-order DS pipe) ----
    bf16x8 pf[2];
#pragma unroll
    for (int tt = 0; tt < 2; ++tt)
      pf[tt] = *(const bf16x8*)&sPa[wave][(tt * 16 + c) * 40 + oPr];
    accD[0] = __builtin_amdgcn_mfma_f32_16x16x32_bf16(pf[0], ones, accD[0], 0, 0, 0);
    accD[1] = __builtin_amdgcn_mfma_f32_16x16x32_bf16(pf[1], ones, accD[1], 0, 0, 0);
#pragma unroll
    for (int dt = 0; dt < 8; ++dt) {
      bf16x8 vf = *(const bf16x8*)(vb + oV + dt * 16 * 32);
      acc[0][dt] = __builtin_amdgcn_mfma_f32_16x16x32_bf16(pf[0], vf, acc[0][dt], 0, 0, 0);
      acc[1][dt] = __builtin_amdgcn_mfma_f32_16x16x32_bf16(pf[1], vf, acc[1][dt], 0, 0, 0);
    }

    __syncthreads();   // staged buf^1 complete + all reads of buf done
  }

  // ---- write partials: num (bf16) + den (fp32, col-replicated in accD) ----
  const size_t pbase = ((size_t)(b * NS + ns)) * T_DIM * D_DIM;
#pragma unroll
  for (int tt = 0; tt < 2; ++tt)
#pragma unroll
    for (int dt = 0; dt < 8; ++dt) {
      unsigned int w01 = cvt_pk_bf16(acc[tt][dt][0], acc[tt][dt][1]);
      unsigned int w23 = cvt_pk_bf16(acc[tt][dt][2], acc[tt][dt][3]);
      size_t a0 = pbase + (size_t)(t0w + tt * 16 + g * 4) * D_DIM + dt * 16 + c;
      accp[a0 + 0 * D_DIM] = (unsigned short)w01;
      accp[a0 + 1 * D_DIM] = (unsigned short)(w01 >> 16);
      accp[a0 + 2 * D_DIM] = (unsigned short)w23;
      accp[a0 + 3 * D_DIM] = (unsigned short)(w23 >> 16);
    }
  if (c == 0) {
#pragma unroll
    for (int tt = 0; tt < 2; ++tt)
#pragma unroll
      for (int r = 0; r < 4; ++r)
        rsp[(b * NS + ns) * T_DIM + t0w + tt * 16 + g * 4 + r] = accD[tt][r];
  }
}

// ---------------- Kernel D: combine split-K partials, normalize ----------------
__global__ void __launch_bounds__(256) k_comb(
    const unsigned short* __restrict__ accp, const float* __restrict__ rsp,
    float* __restrict__ out) {
  int gid = blockIdx.x * 256 + threadIdx.x;
  int base = gid * 4;
  int d = base & 127;
  int t = (base >> 7) & (T_DIM - 1);
  int b = base >> 18;
  float num0 = 0.f, num1 = 0.f, num2 = 0.f, num3 = 0.f, den = 0.f;
#pragma unroll
  for (int ns = 0; ns < NS; ++ns) {
    const unsigned short* p =
        accp + (((size_t)(b * NS + ns)) * T_DIM + t) * D_DIM + d;
    s16x4 v = *(const s16x4*)p;
    num0 += bf2f((unsigned short)v[0]);
    num1 += bf2f((unsigned short)v[1]);
    num2 += bf2f((unsigned short)v[2]);
    num3 += bf2f((unsigned short)v[3]);
    den += rsp[(b * NS + ns) * T_DIM + t];
  }
  float inv = 1.0f / den;
  f32x4 o = (f32x4){num0 * inv, num1 * inv, num2 * inv, num3 * inv};
  *(f32x4*)(out + base) = o;
}

extern "C" void kernel_launch(void* const* d_in, const int* in_sizes, int n_in,
                              void* d_out, int out_size, void* d_ws, size_t ws_size,
                              hipStream_t stream) {
  const float* X = (const float*)d_in[0];  // (8, 2048, 128) fp32
  const float* W = (const float*)d_in[1];  // (128, 64) fp32
  float* out = (float*)d_out;
  char* ws = (char*)d_ws;

  unsigned short* Sb = (unsigned short*)(ws);                 // 32 KB bf16
  float* part        = (float*)(ws + 32768);                  // 2 KB
  unsigned short* Qb = (unsigned short*)(ws + 65536);         // 4 MB bf16 (pre-scaled)
  unsigned short* Xb = (unsigned short*)(ws + 65536 + 4194304);              // 4 MB
  unsigned short* Xt = (unsigned short*)(ws + 65536 + 2 * 4194304);          // 4 MB
  unsigned short* accp = (unsigned short*)(ws + 65536 + 3 * 4194304);        // 16 MB
  float* rsp         = (float*)(ws + 65536 + 3 * 4194304 + 16777216);        // 256 KB
  // total ws use: ~28.9 MB

  k_s<<<64, 256, 0, stream>>>(W, Sb);
  k_prep<<<dim3(T_DIM / 32, B_DIM), 128, 0, stream>>>(X, Sb, Qb, Xb, Xt, part);
  k_attn<<<dim3(T_DIM / 128, NS, B_DIM), 256, 0, stream>>>(Qb, Xb, Xt, part, accp, rsp);
  k_comb<<<(B_DIM * T_DIM * D_DIM / 4) / 256, 256, 0, stream>>>(accp, rsp, out);
}

// Round 9
// 53.836 us; speedup vs baseline: 4.3696x; 1.0295x over previous
//
#include <hip/hip_runtime.h>
#include <hip/hip_bf16.h>
#include <math.h>

#define D_DIM 128
#define R_DIM 64
#define T_DIM 2048
#define B_DIM 8
#define NS 4                       // split-K factor over the s dimension
#define SCHUNK (T_DIM / NS)        // 512
#define SBLK 32                    // s-tile per iteration
#define NIT (SCHUNK / SBLK)        // 16
#define KE_CONST (0.08838834764831845f * 1.4426950408889634f)  // 1/sqrt(128) * log2(e)

typedef __attribute__((ext_vector_type(8))) short bf16x8;
typedef __attribute__((ext_vector_type(4))) short s16x4;
typedef __attribute__((ext_vector_type(4))) float f32x4;

__device__ inline unsigned short f2bf(float f) {
  union { float f; unsigned int u; } v; v.f = f;
  return (unsigned short)((v.u + 0x7FFFu + ((v.u >> 16) & 1u)) >> 16);
}
__device__ inline float bf2f(unsigned short u) {
  union { unsigned int u; float f; } v; v.u = ((unsigned int)u) << 16;
  return v.f;
}
// packed RNE f32->bf16 pair: low half = lo, high half = hi (T12 recipe)
__device__ inline unsigned int cvt_pk_bf16(float lo, float hi) {
  unsigned int r;
  asm("v_cvt_pk_bf16_f32 %0, %1, %2" : "=v"(r) : "v"(lo), "v"(hi));
  return r;
}

// async global->LDS, 16B per lane; LDS dest = wave-uniform base + lane*16
__device__ inline void async16(const short* l, const unsigned short* g) {
  __builtin_amdgcn_global_load_lds(
      (const __attribute__((address_space(1))) unsigned int*)g,
      (__attribute__((address_space(3))) unsigned int*)l, 16, 0, 0);
}

// ---------------- Kernel A: S = W W^T / sqrt(D*R), bf16 out ----------------
__global__ void k_s(const float* __restrict__ W, unsigned short* __restrict__ Sb) {
  int gid = blockIdx.x * 256 + threadIdx.x;
  int i = gid >> 7, j = gid & 127;
  const float* wi = W + i * R_DIM;
  const float* wj = W + j * R_DIM;
  float acc = 0.f;
#pragma unroll 8
  for (int r = 0; r < R_DIM; ++r) acc += wi[r] * wj[r];
  Sb[gid] = f2bf(acc * 0.011048543456039806f);  // 1/sqrt(128*64)
}

// ---------------- Kernel B: MFMA Q = X*S (bf16, pre-scaled), Xb, Xt, trace ----------------
__global__ void __launch_bounds__(128) k_prep(
    const float* __restrict__ X, const unsigned short* __restrict__ Sb,
    unsigned short* __restrict__ Qb, unsigned short* __restrict__ Xb,
    unsigned short* __restrict__ Xt, float* __restrict__ part) {
  const int tid = threadIdx.x;
  const int w = tid >> 6, lane = tid & 63;
  const int g = lane >> 4, c = lane & 15;
  const int b = blockIdx.y;
  const int t0 = blockIdx.x * 32;
  const int tw = t0 + w * 16;           // this wave's 16 rows

  __shared__ __align__(16) short xbT[D_DIM * 32];   // [e][t-local], 8 KB
  __shared__ float red[2];

  // load X rows, cvt to bf16 frags, write Xb, fill xbT transpose
  union FU { unsigned int wd[4]; bf16x8 v; };
  bf16x8 xf[4];
#pragma unroll
  for (int kc = 0; kc < 4; ++kc) {
    const float* xp = X + ((size_t)(b * T_DIM + tw + c)) * D_DIM + kc * 32 + g * 8;
    f32x4 a = *(const f32x4*)xp;
    f32x4 bb = *(const f32x4*)(xp + 4);
    FU f;
    f.wd[0] = cvt_pk_bf16(a[0], a[1]);
    f.wd[1] = cvt_pk_bf16(a[2], a[3]);
    f.wd[2] = cvt_pk_bf16(bb[0], bb[1]);
    f.wd[3] = cvt_pk_bf16(bb[2], bb[3]);
    xf[kc] = f.v;
    *(bf16x8*)(Xb + ((size_t)(b * T_DIM + tw + c)) * D_DIM + kc * 32 + g * 8) = f.v;
#pragma unroll
    for (int jw = 0; jw < 4; ++jw) {
      unsigned int wv = f.wd[jw];
      int e = kc * 32 + g * 8 + jw * 2;
      xbT[(e + 0) * 32 + w * 16 + c] = (short)wv;
      xbT[(e + 1) * 32 + w * 16 + c] = (short)(wv >> 16);
    }
  }

  // MFMA: acc[dc] = X(16 rows) * S, B-frags direct from global (symmetric S)
  f32x4 acc[8];
#pragma unroll
  for (int dc = 0; dc < 8; ++dc) acc[dc] = (f32x4){0.f, 0.f, 0.f, 0.f};
#pragma unroll
  for (int dc = 0; dc < 8; ++dc) {
    bf16x8 sf[4];
#pragma unroll
    for (int kc = 0; kc < 4; ++kc)
      sf[kc] = *(const bf16x8*)(Sb + (size_t)(dc * 16 + c) * D_DIM + kc * 32 + g * 8);
#pragma unroll
    for (int kc = 0; kc < 4; ++kc)
      acc[dc] = __builtin_amdgcn_mfma_f32_16x16x32_bf16(xf[kc], sf[kc], acc[dc], 0, 0, 0);
  }

  __syncthreads();   // xbT complete (both waves)

  // trace partial (unscaled) + store Q pre-scaled by KE as bf16
  float trp = 0.f;
#pragma unroll
  for (int dc = 0; dc < 8; ++dc)
#pragma unroll
    for (int r = 0; r < 4; ++r) {
      float q = acc[dc][r];
      float x = bf2f((unsigned short)xbT[(dc * 16 + c) * 32 + w * 16 + g * 4 + r]);
      trp += q * x;
      unsigned int pk = cvt_pk_bf16(q * KE_CONST, 0.f);
      Qb[((size_t)(b * T_DIM + tw + g * 4 + r)) * D_DIM + dc * 16 + c] = (unsigned short)pk;
    }

  // write Xt from xbT: 4 passes x 32 rows, b128 in / b128 out
#pragma unroll
  for (int p = 0; p < 4; ++p) {
    int row = p * 32 + (tid >> 2);
    bf16x8 v = *(const bf16x8*)&xbT[row * 32 + (tid & 3) * 8];
    *(bf16x8*)(Xt + ((size_t)(b * D_DIM + row)) * T_DIM + t0 + (tid & 3) * 8) = v;
  }

  // reduce trace partial: wave shuffle -> cross-wave via LDS
  trp += __shfl_xor(trp, 1); trp += __shfl_xor(trp, 2);
  trp += __shfl_xor(trp, 4); trp += __shfl_xor(trp, 8);
  trp += __shfl_xor(trp, 16); trp += __shfl_xor(trp, 32);
  if (lane == 0) red[w] = trp;
  __syncthreads();
  if (tid == 0) part[b * 64 + blockIdx.x] = red[0] + red[1];
}

// ---------------- Kernel C: flash attention, 4 waves/block, LDS-staged ----------------
// Byte-identical internals to the R6 known-pass kernel (staged K AND V);
// ONLY the block-index decode is changed: flat 1D grid with bid&7 == batch,
// pinning each batch's L2 working set to one XCD.
__global__ void __launch_bounds__(256, 2) k_attn(
    const unsigned short* __restrict__ Qb, const unsigned short* __restrict__ Xb,
    const unsigned short* __restrict__ Xt, const float* __restrict__ part,
    unsigned short* __restrict__ accp, float* __restrict__ rsp) {
  const int tid = threadIdx.x;
  const int wave = tid >> 6, lane = tid & 63;
  const int g = lane >> 4, c = lane & 15;
  // XCD-aware decomposition (delta (a)): lin = tile*32 + ns*8 + b, bijective.
  const int lin = blockIdx.x;
  const int b = lin & 7;
  const int kk = lin >> 3;
  const int ns = kk & 3;
  const int t0w = (kk >> 2) * 128 + wave * 32;   // 32 q-rows per wave

  const unsigned short* Qbb = Qb + (size_t)b * T_DIM * D_DIM;
  const unsigned short* Xbb = Xb + (size_t)b * T_DIM * D_DIM;
  const unsigned short* Xtb = Xt + (size_t)b * D_DIM * T_DIM;

  // inline trace reduction (per-wave redundant, L2-hot)
  float tv = part[b * 64 + lane];
  tv += __shfl_xor(tv, 1); tv += __shfl_xor(tv, 2);
  tv += __shfl_xor(tv, 4); tv += __shfl_xor(tv, 8);
  tv += __shfl_xor(tv, 16); tv += __shfl_xor(tv, 32);
  const float ctrK = tv * (1.0f / T_DIM) * KE_CONST;

  __shared__ __align__(16) short sKs[2][SBLK * D_DIM];   // 2 x 8 KB
  __shared__ __align__(16) short sVs[2][D_DIM * SBLK];   // 2 x 8 KB
  __shared__ __align__(16) short sPa[4][32 * 40];        // per-wave P, 80B rows, grp-XOR swz

  // swizzled ds_read offsets (shorts)
  int oK[4], oV;
#pragma unroll
  for (int kc = 0; kc < 4; ++kc)
    oK[kc] = c * 128 + (((kc * 4 + g) ^ (c & 7)) * 8);
  oV = c * 32 + ((g ^ (c & 3)) * 8);
  const int oPr = (g ^ ((c >> 2) & 3)) * 8;  // P-read grp slot

  // Q fragments (bf16, pre-scaled by KE)
  bf16x8 qf[2][4];
#pragma unroll
  for (int tt = 0; tt < 2; ++tt)
#pragma unroll
    for (int kc = 0; kc < 4; ++kc)
      qf[tt][kc] = *(const bf16x8*)(Qbb + (size_t)(t0w + tt * 16 + c) * D_DIM + kc * 32 + g * 8);

  bf16x8 ones;
#pragma unroll
  for (int j = 0; j < 8; ++j) ones[j] = (short)0x3F80;  // bf16 1.0

  f32x4 acc[2][8];
#pragma unroll
  for (int tt = 0; tt < 2; ++tt)
#pragma unroll
    for (int dt = 0; dt < 8; ++dt) acc[tt][dt] = (f32x4){0.f, 0.f, 0.f, 0.f};
  f32x4 accD[2] = {(f32x4){0.f, 0.f, 0.f, 0.f}, (f32x4){0.f, 0.f, 0.f, 0.f}};

  const int s_beg = ns * SCHUNK;

  // staging: 1024 16B chunks split over 4 waves (2 K-issues + 2 V-issues per lane)
  auto stage = [&](int buf, int sb) {
#pragma unroll
    for (int q = 0; q < 2; ++q) {
      int j = wave * 128 + q * 64 + lane;
      int row = j >> 4, sc = j & 15;
      int lc = sc ^ (row & 7);
      async16(&sKs[buf][(wave * 128 + q * 64) * 8],
              Xbb + (size_t)(sb + row) * D_DIM + lc * 8);
    }
#pragma unroll
    for (int q = 0; q < 2; ++q) {
      int j = wave * 128 + q * 64 + lane;
      int row = j >> 2, sc = j & 3;
      int lc = sc ^ (row & 3);
      async16(&sVs[buf][(wave * 128 + q * 64) * 8],
              Xtb + (size_t)row * T_DIM + sb + lc * 8);
    }
  };

  stage(0, s_beg);
  __syncthreads();

  for (int it = 0; it < NIT; ++it) {
    const int buf = it & 1;
    const int sb = s_beg + it * SBLK;
    if (it < NIT - 1) stage(buf ^ 1, sb + SBLK);

    const short* kb = &sKs[buf][0];
    const short* vb = &sVs[buf][0];
    const bool isdiag = (sb == t0w);   // wave-uniform: only iter containing s==t

    // ---- QK^T + exp2 + stage P (conflict-free grp-XOR layout) ----
#pragma unroll
    for (int st = 0; st < 2; ++st) {
      bf16x8 kf[4];
#pragma unroll
      for (int kc = 0; kc < 4; ++kc)
        kf[kc] = *(const bf16x8*)(kb + oK[kc] + st * 16 * 128);
      f32x4 sc0 = (f32x4){0.f, 0.f, 0.f, 0.f};
      f32x4 sc1 = (f32x4){0.f, 0.f, 0.f, 0.f};
#pragma unroll
      for (int kc = 0; kc < 4; ++kc) {
        sc0 = __builtin_amdgcn_mfma_f32_16x16x32_bf16(qf[0][kc], kf[kc], sc0, 0, 0, 0);
        sc1 = __builtin_amdgcn_mfma_f32_16x16x32_bf16(qf[1][kc], kf[kc], sc1, 0, 0, 0);
      }
      const int gp = ((st * 2 + (c >> 3)) ^ g) * 8 + (c & 7);  // swizzled col slot
#pragma unroll
      for (int tt = 0; tt < 2; ++tt) {
        f32x4 sc = tt ? sc1 : sc0;
        float p[4];
#pragma unroll
        for (int r = 0; r < 4; ++r) {
          float v = sc[r];
          if (isdiag && (st * 16 + c) == (tt * 16 + g * 4 + r)) v -= ctrK;
          p[r] = exp2f(v);
        }
        unsigned int w01 = cvt_pk_bf16(p[0], p[1]);
        unsigned int w23 = cvt_pk_bf16(p[2], p[3]);
        short* pw = &sPa[wave][(tt * 16 + g * 4) * 40 + gp];
        pw[0 * 40] = (short)w01;
        pw[1 * 40] = (short)(w01 >> 16);
        pw[2 * 40] = (short)w23;
        pw[3 * 40] = (short)(w23 >> 16);
      }
    }

    // ---- P·V + den via ones-MFMA (same-wave LDS, in-order DS pipe) ----
    bf16x8 pf[2];
#pragma unroll
    for (int tt = 0; tt < 2; ++tt)
      pf[tt] = *(const bf16x8*)&sPa[wave][(tt * 16 + c) * 40 + oPr];
    accD[0] = __builtin_amdgcn_mfma_f32_16x16x32_bf16(pf[0], ones, accD[0], 0, 0, 0);
    accD[1] = __builtin_amdgcn_mfma_f32_16x16x32_bf16(pf[1], ones, accD[1], 0, 0, 0);
#pragma unroll
    for (int dt = 0; dt < 8; ++dt) {
      bf16x8 vf = *(const bf16x8*)(vb + oV + dt * 16 * 32);
      acc[0][dt] = __builtin_amdgcn_mfma_f32_16x16x32_bf16(pf[0], vf, acc[0][dt], 0, 0, 0);
      acc[1][dt] = __builtin_amdgcn_mfma_f32_16x16x32_bf16(pf[1], vf, acc[1][dt], 0, 0, 0);
    }

    __syncthreads();   // staged buf^1 complete + all reads of buf done
  }

  // ---- write partials: num (bf16) + den (fp32, col-replicated in accD) ----
  const size_t pbase = ((size_t)(b * NS + ns)) * T_DIM * D_DIM;
#pragma unroll
  for (int tt = 0; tt < 2; ++tt)
#pragma unroll
    for (int dt = 0; dt < 8; ++dt) {
      unsigned int w01 = cvt_pk_bf16(acc[tt][dt][0], acc[tt][dt][1]);
      unsigned int w23 = cvt_pk_bf16(acc[tt][dt][2], acc[tt][dt][3]);
      size_t a0 = pbase + (size_t)(t0w + tt * 16 + g * 4) * D_DIM + dt * 16 + c;
      accp[a0 + 0 * D_DIM] = (unsigned short)w01;
      accp[a0 + 1 * D_DIM] = (unsigned short)(w01 >> 16);
      accp[a0 + 2 * D_DIM] = (unsigned short)w23;
      accp[a0 + 3 * D_DIM] = (unsigned short)(w23 >> 16);
    }
  if (c == 0) {
#pragma unroll
    for (int tt = 0; tt < 2; ++tt)
#pragma unroll
      for (int r = 0; r < 4; ++r)
        rsp[(b * NS + ns) * T_DIM + t0w + tt * 16 + g * 4 + r] = accD[tt][r];
  }
}

// ---------------- Kernel D: combine split-K partials, normalize ----------------
// Delta (c): flat grid, bid&7 == b so accp/rsp reads hit the XCD-local L2.
__global__ void __launch_bounds__(256) k_comb(
    const unsigned short* __restrict__ accp, const float* __restrict__ rsp,
    float* __restrict__ out) {
  const int lin = blockIdx.x;
  const int b = lin & 7;
  const int kk = lin >> 3;                      // 0..255
  int ib = kk * 1024 + threadIdx.x * 4;         // element base within batch
  int d = ib & 127;
  int t = ib >> 7;
  float num0 = 0.f, num1 = 0.f, num2 = 0.f, num3 = 0.f, den = 0.f;
#pragma unroll
  for (int ns = 0; ns < NS; ++ns) {
    const unsigned short* p =
        accp + (((size_t)(b * NS + ns)) * T_DIM + t) * D_DIM + d;
    s16x4 v = *(const s16x4*)p;
    num0 += bf2f((unsigned short)v[0]);
    num1 += bf2f((unsigned short)v[1]);
    num2 += bf2f((unsigned short)v[2]);
    num3 += bf2f((unsigned short)v[3]);
    den += rsp[(b * NS + ns) * T_DIM + t];
  }
  float inv = 1.0f / den;
  f32x4 o = (f32x4){num0 * inv, num1 * inv, num2 * inv, num3 * inv};
  *(f32x4*)(out + ((size_t)b * T_DIM * D_DIM + ib)) = o;
}

extern "C" void kernel_launch(void* const* d_in, const int* in_sizes, int n_in,
                              void* d_out, int out_size, void* d_ws, size_t ws_size,
                              hipStream_t stream) {
  const float* X = (const float*)d_in[0];  // (8, 2048, 128) fp32
  const float* W = (const float*)d_in[1];  // (128, 64) fp32
  float* out = (float*)d_out;
  char* ws = (char*)d_ws;

  unsigned short* Sb = (unsigned short*)(ws);                 // 32 KB bf16
  float* part        = (float*)(ws + 32768);                  // 2 KB
  unsigned short* Qb = (unsigned short*)(ws + 65536);         // 4 MB bf16 (pre-scaled)
  unsigned short* Xb = (unsigned short*)(ws + 65536 + 4194304);              // 4 MB
  unsigned short* Xt = (unsigned short*)(ws + 65536 + 2 * 4194304);          // 4 MB
  unsigned short* accp = (unsigned short*)(ws + 65536 + 3 * 4194304);        // 16 MB
  float* rsp         = (float*)(ws + 65536 + 3 * 4194304 + 16777216);        // 256 KB
  // total ws use: ~28.9 MB

  k_s<<<64, 256, 0, stream>>>(W, Sb);
  k_prep<<<dim3(T_DIM / 32, B_DIM), 128, 0, stream>>>(X, Sb, Qb, Xb, Xt, part);
  k_attn<<<(T_DIM / 128) * NS * B_DIM, 256, 0, stream>>>(Qb, Xb, Xt, part, accp, rsp);
  k_comb<<<B_DIM * 256, 256, 0, stream>>>(accp, rsp, out);
}